// Round 9
// baseline (110.656 us; speedup 1.0000x reference)
//
#include <hip/hip_runtime.h>

#define BB 8
#define NN 4096
#define CCH 512
#define KK 32
#define CLS 21
#define BN_EPS 1e-3f

#define TPB 512
#define CHUNK 64
#define NBLK (NN / CHUNK)   // 64 -> grid (64,8) = 512 blocks = 2/CU

typedef _Float16 f16;
typedef _Float16 f16x4 __attribute__((ext_vector_type(4)));
typedef _Float16 f16x8 __attribute__((ext_vector_type(8)));
typedef float f32x4 __attribute__((ext_vector_type(4)));

#define NP 36    // wtT row pitch in f16

// LDS carve (bytes)
#define LB_CWB  0                         // f16[2][16][64][8] 32768
#define LB_WTT  32768                     // f16[32][NP]        2304
#define LB_RED  35072                     // f32[6][64][4]      6144
#define LB_XSQ  41216                     // f32[2ch][2m][16]    256
#define LB_CSQ  41472                     // f32[32]             128
#define LB_NSF  41600                     // f32[32]             128
#define LB_WSQ  41728                     // f32[2w][2kt][16]    256
#define LB_TOT  41984

// ws layout (floats)
#define WS_P    0                                  // [NBLK][BB][CCH][KK]
#define WS_WSP  (NBLK * BB * CCH * KK)             // 8388608
#define WS_ENC  (WS_WSP + NBLK * BB * KK)          // 8404992
#define WS_ATTN (WS_ENC + BB * CCH)                // 8409088
#define WS_END  (WS_ATTN + BB * CCH)

template <int CTRL>
__device__ __forceinline__ float dpp_add(float v) {
    int r = __builtin_amdgcn_update_dpp(0, __builtin_bit_cast(int, v),
                                        CTRL, 0xF, 0xF, true);
    return v + __builtin_bit_cast(float, r);
}
template <int CTRL>
__device__ __forceinline__ float dpp_max(float v) {
    int r = __builtin_amdgcn_update_dpp(0, __builtin_bit_cast(int, v),
                                        CTRL, 0xF, 0xF, true);
    return fmaxf(v, __builtin_bit_cast(float, r));
}
__device__ __forceinline__ float rowsum16(float v) {
    v = dpp_add<0x128>(v); v = dpp_add<0x124>(v);
    v = dpp_add<0x122>(v); v = dpp_add<0x121>(v);
    return v;
}
__device__ __forceinline__ float rowmax16(float v) {
    v = dpp_max<0x128>(v); v = dpp_max<0x124>(v);
    v = dpp_max<0x122>(v); v = dpp_max<0x121>(v);
    return v;
}

// ---------------------------------------------------------------------------
// Kernel A (MFMA, load-batched): fused cross -> softmax -> wx partials.
// cross roles: m=w&1, kt=(w>>1)&1, ch=w>>2.  All 16 A-frag float4 loads are
// issued into a register array BEFORE any convert/MFMA (keeps ~16 loads in
// flight per wave); same for the 32 wx B-gather dwords.
// ---------------------------------------------------------------------------
__global__ __launch_bounds__(TPB, 2) void enc_mfma(
    const float* __restrict__ x, const float* __restrict__ cw,
    const float* __restrict__ sf, float* __restrict__ ws)
{
    extern __shared__ char sm[];
    f16*   cwB  = (f16*)(sm + LB_CWB);
    f16*   wtT  = (f16*)(sm + LB_WTT);
    float* red  = (float*)(sm + LB_RED);
    float* xsq  = (float*)(sm + LB_XSQ);
    float* csqL = (float*)(sm + LB_CSQ);
    float* nsfL = (float*)(sm + LB_NSF);
    float* wsq  = (float*)(sm + LB_WSQ);

    const int t = threadIdx.x;
    const int b = blockIdx.y;
    const int w = t >> 6;
    const int l = t & 63;
    const int a = l & 15;
    const int g = l >> 4;

    // ---- stage cwB in B-fragment layout (once per block) ----
    for (int si = 0; si < 4; ++si) {
        const int s     = si * 512 + t;        // 0..2047
        const int lane  = s & 63;
        const int cstep = (s >> 6) & 15;
        const int kt    = s >> 10;
        const int k     = (lane & 15) + 16 * kt;
        const int c0    = cstep * 32 + (lane >> 4) * 8;
        f16x8 v;
#pragma unroll
        for (int i = 0; i < 8; ++i) v[i] = (f16)cw[(c0 + i) * KK + k];
        *reinterpret_cast<f16x8*>(cwB + ((size_t)(kt * 16 + cstep) * 64 + lane) * 8) = v;
    }
    // ---- cwsq partials (red used as scratch) ----
    if (t < 256) {
        const int k = t & 31, part = t >> 5;
        float sacc = 0.f;
        for (int c = part * 64; c < part * 64 + 64; ++c) {
            const float v = cw[c * KK + k];
            sacc += v * v;
        }
        red[part * 32 + k] = sacc;
    }
    __syncthreads();
    if (t < 32) {
        float sacc = 0.f;
#pragma unroll
        for (int p = 0; p < 8; ++p) sacc += red[p * 32 + t];
        csqL[t] = sacc;
        nsfL[t] = -sf[t];
    }
    __syncthreads();

    const int m_  = w & 1;
    const int kt_ = (w >> 1) & 1;
    const int ch_ = w >> 2;

    f32x4 acc[4][2];
#pragma unroll
    for (int ct = 0; ct < 4; ++ct)
#pragma unroll
        for (int kt = 0; kt < 2; ++kt) acc[ct][kt] = (f32x4){0.f, 0.f, 0.f, 0.f};
    float wsacc0 = 0.f, wsacc1 = 0.f;

    for (int tile = 0; tile < 2; ++tile) {
        const int n0 = blockIdx.x * CHUNK + tile * 32;

        // ---- cross: batch-issue ALL 16 A loads, then convert+MFMA ----
        f32x4 d = {0.f, 0.f, 0.f, 0.f};
        {
            const float* xrow = x + (size_t)(b * NN + n0 + 16 * m_ + a) * CCH;
            float4 u[16];
#pragma unroll
            for (int cs = 0; cs < 8; ++cs) {
                const int c0 = (ch_ * 8 + cs) * 32 + g * 8;
                u[2 * cs]     = *reinterpret_cast<const float4*>(xrow + c0);
                u[2 * cs + 1] = *reinterpret_cast<const float4*>(xrow + c0 + 4);
            }
            float sq = 0.f;
#pragma unroll
            for (int cs = 0; cs < 8; ++cs) {
                const float4 u0 = u[2 * cs], u1 = u[2 * cs + 1];
                if (kt_ == 0)
                    sq += u0.x*u0.x + u0.y*u0.y + u0.z*u0.z + u0.w*u0.w
                        + u1.x*u1.x + u1.y*u1.y + u1.z*u1.z + u1.w*u1.w;
                const f16x8 af = {(f16)u0.x, (f16)u0.y, (f16)u0.z, (f16)u0.w,
                                  (f16)u1.x, (f16)u1.y, (f16)u1.z, (f16)u1.w};
                const f16x8 bf = *reinterpret_cast<const f16x8*>(
                    cwB + ((size_t)(kt_ * 16 + (ch_ * 8 + cs)) * 64 + l) * 8);
                d = __builtin_amdgcn_mfma_f32_16x16x32_f16(af, bf, d, 0, 0, 0);
            }
            if (kt_ == 0) {
                sq += __shfl_xor(sq, 16);
                sq += __shfl_xor(sq, 32);
                if (l < 16) xsq[(ch_ * 2 + m_) * 16 + l] = sq;
            }
        }
        if (w >= 2)
            *reinterpret_cast<f32x4*>(red + ((w - 2) * 64 + l) * 4) = d;
        __syncthreads();   // B1: xsq, red ready

        // ---- softmax (waves 0,1; m = w) ----
        if (w < 2) {
            const f32x4 r0 = *reinterpret_cast<const f32x4*>(red + ((w + 2) * 64 + l) * 4);
            const f32x4 r1 = *reinterpret_cast<const f32x4*>(red + ((w    ) * 64 + l) * 4);
            const f32x4 r2 = *reinterpret_cast<const f32x4*>(red + ((w + 4) * 64 + l) * 4);
            const f32x4 d0 = d + r0;
            const f32x4 d1 = r1 + r2;
            const float cq0 = csqL[a],  cq1 = csqL[a + 16];
            const float sf0 = nsfL[a],  sf1 = nsfL[a + 16];
#pragma unroll
            for (int r = 0; r < 4; ++r) {
                const int row = 4 * g + r;
                const float xs = xsq[(0 * 2 + w) * 16 + row]
                               + xsq[(1 * 2 + w) * 16 + row];
                const float l0 = (xs - 2.f * d0[r] + cq0) * sf0;
                const float l1 = (xs - 2.f * d1[r] + cq1) * sf1;
                const float mx = rowmax16(fmaxf(l0, l1));
                const float e0 = __expf(l0 - mx);
                const float e1 = __expf(l1 - mx);
                const float inv = 1.f / rowsum16(e0 + e1);
                const float w0 = e0 * inv, w1 = e1 * inv;
                wsacc0 += w0; wsacc1 += w1;
                const int n = 16 * w + row;
                wtT[(a     ) * NP + n] = (f16)w0;
                wtT[(a + 16) * NP + n] = (f16)w1;
            }
        }
        __syncthreads();   // B2: wtT ready

        // ---- wx: batch-gather ALL 32 B dwords, then convert+MFMA ----
        {
            union { f16x8 v; f16x4 h[2]; } A0, A1;
            A0.h[0] = *reinterpret_cast<const f16x4*>(wtT + (a     ) * NP + g * 8);
            A0.h[1] = *reinterpret_cast<const f16x4*>(wtT + (a     ) * NP + g * 8 + 4);
            A1.h[0] = *reinterpret_cast<const f16x4*>(wtT + (a + 16) * NP + g * 8);
            A1.h[1] = *reinterpret_cast<const f16x4*>(wtT + (a + 16) * NP + g * 8 + 4);
            const float* xb = x + (size_t)(b * NN + n0 + g * 8) * CCH;
            float xr[4][8];
#pragma unroll
            for (int ct = 0; ct < 4; ++ct) {
                const int c = w * 64 + ct * 16 + a;
#pragma unroll
                for (int i = 0; i < 8; ++i)
                    xr[ct][i] = xb[(size_t)i * CCH + c];
            }
#pragma unroll
            for (int ct = 0; ct < 4; ++ct) {
                const f16x8 B = {(f16)xr[ct][0], (f16)xr[ct][1], (f16)xr[ct][2],
                                 (f16)xr[ct][3], (f16)xr[ct][4], (f16)xr[ct][5],
                                 (f16)xr[ct][6], (f16)xr[ct][7]};
                acc[ct][0] = __builtin_amdgcn_mfma_f32_16x16x32_f16(A0.v, B, acc[ct][0], 0, 0, 0);
                acc[ct][1] = __builtin_amdgcn_mfma_f32_16x16x32_f16(A1.v, B, acc[ct][1], 0, 0, 0);
            }
        }
        __syncthreads();   // B3: protect wtT/red/xsq for next tile
    }

    // ---- epilogue: stream wx partials ----
    {
        float* pp = ws + WS_P + ((size_t)(blockIdx.x * BB + b)) * CCH * KK;
#pragma unroll
        for (int ct = 0; ct < 4; ++ct) {
            const int c = w * 64 + ct * 16 + a;
#pragma unroll
            for (int kt = 0; kt < 2; ++kt)
                *reinterpret_cast<f32x4*>(pp + (size_t)c * KK + kt * 16 + g * 4) = acc[ct][kt];
        }
    }
    if (w < 2) {
        float s0 = wsacc0, s1 = wsacc1;
        s0 += __shfl_xor(s0, 16); s0 += __shfl_xor(s0, 32);
        s1 += __shfl_xor(s1, 16); s1 += __shfl_xor(s1, 32);
        if (l < 16) {
            wsq[(w * 2 + 0) * 16 + l] = s0;
            wsq[(w * 2 + 1) * 16 + l] = s1;
        }
    }
    __syncthreads();
    if (t < 32) {
        const int kt = t >> 4, kk_ = t & 15;
        ws[WS_WSP + ((size_t)blockIdx.x * BB + b) * KK + t] =
            wsq[(0 * 2 + kt) * 16 + kk_] + wsq[(1 * 2 + kt) * 16 + kk_];
    }
}

// ---------------------------------------------------------------------------
// Kernel R: reduce partials + enc -> BN -> ReLU -> sum_k => encv
// grid (64, 8), 256 thr; thread = (c = cs*8 + t>>5, k = t&31); 8-way ILP.
// ---------------------------------------------------------------------------
__global__ __launch_bounds__(256) void reduce_encv(
    float* __restrict__ ws, const float* __restrict__ cw,
    const float* __restrict__ gamma, const float* __restrict__ beta,
    const float* __restrict__ mean, const float* __restrict__ var)
{
    __shared__ float wsum_s[KK];
    const int b  = blockIdx.y;
    const int cs = blockIdx.x;
    const int t  = threadIdx.x;

    if (t < KK) {
        float s0 = 0.f, s1 = 0.f, s2 = 0.f, s3 = 0.f;
        for (int ch = 0; ch < NBLK; ch += 4) {
            s0 += ws[WS_WSP + ((size_t)(ch + 0) * BB + b) * KK + t];
            s1 += ws[WS_WSP + ((size_t)(ch + 1) * BB + b) * KK + t];
            s2 += ws[WS_WSP + ((size_t)(ch + 2) * BB + b) * KK + t];
            s3 += ws[WS_WSP + ((size_t)(ch + 3) * BB + b) * KK + t];
        }
        wsum_s[t] = s0 + s1 + s2 + s3;
    }
    __syncthreads();

    const int c = cs * 8 + (t >> 5);
    const int k = t & 31;
    const float* p = ws + WS_P + ((size_t)b * CCH + c) * KK + k;
    const size_t stride = (size_t)BB * CCH * KK;

    float a0 = 0.f, a1 = 0.f, a2 = 0.f, a3 = 0.f;
    float a4 = 0.f, a5 = 0.f, a6 = 0.f, a7 = 0.f;
#pragma unroll
    for (int ch = 0; ch < NBLK; ch += 8) {
        a0 += p[(ch + 0) * stride];
        a1 += p[(ch + 1) * stride];
        a2 += p[(ch + 2) * stride];
        a3 += p[(ch + 3) * stride];
        a4 += p[(ch + 4) * stride];
        a5 += p[(ch + 5) * stride];
        a6 += p[(ch + 6) * stride];
        a7 += p[(ch + 7) * stride];
    }
    const float v = ((a0 + a1) + (a2 + a3)) + ((a4 + a5) + (a6 + a7));

    const float g  = gamma[c] * rsqrtf(var[c] + BN_EPS);
    float r = fmaxf((v - cw[c * KK + k] * wsum_s[k] - mean[c]) * g + beta[c], 0.f);
    r += __shfl_xor(r, 1);
    r += __shfl_xor(r, 2);
    r += __shfl_xor(r, 4);
    r += __shfl_xor(r, 8);
    r += __shfl_xor(r, 16);
    if (k == 0) ws[WS_ENC + (size_t)b * CCH + c] = r;
}

// ---------------------------------------------------------------------------
// Kernel B2: attn = sigmoid(encv @ w_enc + b_enc) ; se = sigmoid(encv @ w_se + b_se)
// ---------------------------------------------------------------------------
__global__ __launch_bounds__(256) void attn_se_kernel(
    const float* __restrict__ enc, float* __restrict__ attn,
    const float* __restrict__ w_enc, const float* __restrict__ b_enc,
    const float* __restrict__ w_se, const float* __restrict__ b_se,
    float* __restrict__ out)
{
    __shared__ float ev[CCH];
    __shared__ float red[4][64];
    const int b   = blockIdx.y;
    const int cgb = blockIdx.x;
    const int t   = threadIdx.x;
    ev[t]       = enc[(size_t)b * CCH + t];
    ev[t + 256] = enc[(size_t)b * CCH + 256 + t];
    __syncthreads();
    if (cgb < 8) {
        const int c2 = cgb * 64 + (t & 63);
        const int p  = t >> 6;
        float a = 0.f;
#pragma unroll 4
        for (int i = 0; i < 128; ++i) {
            const int c = p * 128 + i;
            a += ev[c] * w_enc[c * CCH + c2];
        }
        red[p][t & 63] = a;
        __syncthreads();
        if (t < 64) {
            const float v = red[0][t] + red[1][t] + red[2][t] + red[3][t]
                          + b_enc[cgb * 64 + t];
            attn[(size_t)b * CCH + cgb * 64 + t] = 1.f / (1.f + __expf(-v));
        }
    } else if (t < 8 * CLS) {
        const int j = t >> 3, p = t & 7;
        float a = 0.f;
        for (int c = p; c < CCH; c += 8) a += ev[c] * w_se[c * CLS + j];
        a += __shfl_xor(a, 1);
        a += __shfl_xor(a, 2);
        a += __shfl_xor(a, 4);
        if (p == 0)
            out[(size_t)BB * NN * CCH + b * CLS + j] =
                1.f / (1.f + __expf(-(a + b_se[j])));
    }
}

// ---------------------------------------------------------------------------
// Kernel C: featuremaps = attn[b,c] * x
// ---------------------------------------------------------------------------
__global__ __launch_bounds__(256) void scale_out(
    const float* __restrict__ x, const float* __restrict__ attn,
    float* __restrict__ out)
{
    const int gid = blockIdx.x * 256 + threadIdx.x;
    const int c4  = (gid & 127) << 2;
#pragma unroll
    for (int b = 0; b < BB; ++b) {
        const size_t f = ((size_t)b << 19) + (size_t)gid;
        const float4 xv = *reinterpret_cast<const float4*>(x + 4 * f);
        const float4 av = *reinterpret_cast<const float4*>(attn + (size_t)b * CCH + c4);
        float4 o;
        o.x = xv.x * av.x; o.y = xv.y * av.y; o.z = xv.z * av.z; o.w = xv.w * av.w;
        *reinterpret_cast<float4*>(out + 4 * f) = o;
    }
}

// ---------------------------------------------------------------------------
extern "C" void kernel_launch(void* const* d_in, const int* in_sizes, int n_in,
                              void* d_out, int out_size, void* d_ws, size_t ws_size,
                              hipStream_t stream)
{
    const float* x     = (const float*)d_in[0];
    const float* cw    = (const float*)d_in[1];
    const float* sf    = (const float*)d_in[2];
    const float* gamma = (const float*)d_in[3];
    const float* beta  = (const float*)d_in[4];
    const float* mean  = (const float*)d_in[5];
    const float* var   = (const float*)d_in[6];
    const float* w_enc = (const float*)d_in[7];
    const float* b_enc = (const float*)d_in[8];
    const float* w_se  = (const float*)d_in[9];
    const float* b_se  = (const float*)d_in[10];
    float* out = (float*)d_out;
    float* ws  = (float*)d_ws;

    enc_mfma<<<dim3(NBLK, BB), TPB, LB_TOT, stream>>>(x, cw, sf, ws);
    reduce_encv<<<dim3(64, BB), 256, 0, stream>>>(ws, cw, gamma, beta, mean, var);
    attn_se_kernel<<<dim3(9, BB), 256, 0, stream>>>(
        ws + WS_ENC, ws + WS_ATTN, w_enc, b_enc, w_se, b_se, out);
    scale_out<<<2048, 256, 0, stream>>>(x, ws + WS_ATTN, out);
}

// Round 10
// 104.404 us; speedup vs baseline: 1.0599x; 1.0599x over previous
//
#include <hip/hip_runtime.h>

#define BB 8
#define NN 4096
#define CCH 512
#define KK 32
#define CLS 21
#define BN_EPS 1e-3f

#define CHUNK 64
#define NBLK (NN / CHUNK)   // 64

typedef _Float16 f16;
typedef _Float16 f16x8 __attribute__((ext_vector_type(8)));
typedef float f32x4 __attribute__((ext_vector_type(4)));

// ws layout (floats)
#define WS_P    0                                  // [NBLK][BB][CCH][KK] fp32 partials
#define WS_WSP  (NBLK * BB * CCH * KK)             // 8388608  [NBLK][BB][KK]
#define WS_ENC  (WS_WSP + NBLK * BB * KK)          // 8404992  [BB][CCH]
#define WS_ATTN (WS_ENC + BB * CCH)                // 8409088  [BB][CCH]
#define WS_CWB  (WS_ATTN + BB * CCH)               // 8413184  f16[2048*8] = 8192 floats
#define WS_CSQ  (WS_CWB + 8192)                    // 8421376  [32]
#define WS_NSF  (WS_CSQ + KK)                      // 8421408  [32]
#define WS_END  (WS_NSF + KK)

template <int CTRL>
__device__ __forceinline__ float dpp_add(float v) {
    int r = __builtin_amdgcn_update_dpp(0, __builtin_bit_cast(int, v),
                                        CTRL, 0xF, 0xF, true);
    return v + __builtin_bit_cast(float, r);
}
template <int CTRL>
__device__ __forceinline__ float dpp_max(float v) {
    int r = __builtin_amdgcn_update_dpp(0, __builtin_bit_cast(int, v),
                                        CTRL, 0xF, 0xF, true);
    return fmaxf(v, __builtin_bit_cast(float, r));
}
__device__ __forceinline__ float rowsum16(float v) {
    v = dpp_add<0x128>(v); v = dpp_add<0x124>(v);
    v = dpp_add<0x122>(v); v = dpp_add<0x121>(v);
    return v;
}
__device__ __forceinline__ float rowmax16(float v) {
    v = dpp_max<0x128>(v); v = dpp_max<0x124>(v);
    v = dpp_max<0x122>(v); v = dpp_max<0x121>(v);
    return v;
}

// ---------------------------------------------------------------------------
// Prep: cwB (B-fragment-layout f16 codewords), csq, nsf -> global ws.
// blocks 0..7: 256 cwB slots each; block 8: csq/nsf.
// ---------------------------------------------------------------------------
__global__ __launch_bounds__(256) void prep_kernel(
    const float* __restrict__ cw, const float* __restrict__ sf,
    float* __restrict__ ws)
{
    const int blk = blockIdx.x;
    const int t = threadIdx.x;
    if (blk < 8) {
        const int s     = blk * 256 + t;       // 0..2047
        const int lane  = s & 63;
        const int cstep = (s >> 6) & 15;
        const int kt    = s >> 10;
        const int k     = (lane & 15) + 16 * kt;
        const int c0    = cstep * 32 + (lane >> 4) * 8;
        f16x8 v;
#pragma unroll
        for (int i = 0; i < 8; ++i) v[i] = (f16)cw[(c0 + i) * KK + k];
        reinterpret_cast<f16x8*>(ws + WS_CWB)[s] = v;
    } else {
        __shared__ float red[8][KK];
        const int k = t & 31, part = t >> 5;
        float s = 0.f;
        for (int c = part * 64; c < part * 64 + 64; ++c) {
            const float v = cw[c * KK + k];
            s += v * v;
        }
        red[part][k] = s;
        __syncthreads();
        if (t < KK) {
            float acc = 0.f;
#pragma unroll
            for (int p = 0; p < 8; ++p) acc += red[p][t];
            ws[WS_CSQ + t] = acc;
            ws[WS_NSF + t] = -sf[t];
        }
    }
}

// ---------------------------------------------------------------------------
// Kernel A: per-wave-independent cross+softmax, single barrier, then wx.
// grid (NBLK, BB, 2): z = 256-c half for wx (cross duplicated, it's cheap).
// Wave w owns rows n0 + w*16 .. +15 for cross/softmax (all 512 c, all 32 k).
// wx: A = wexch[k][n] (LDS b128), B = x gather from global (L1/L2-hot).
// ---------------------------------------------------------------------------
__global__ __launch_bounds__(256, 4) void enc_mfma(
    const float* __restrict__ x, float* __restrict__ ws)
{
    __shared__ f16  wexch[32 * 72];   // [k][64 n], pitch 72 f16 (144 B, 16B-mult)
    __shared__ float wsq[4][KK];

    const int t = threadIdx.x;
    const int w = t >> 6, l = t & 63, a = l & 15, g = l >> 4;
    const int chunk = blockIdx.x, b = blockIdx.y, z = blockIdx.z;
    const int n0 = chunk * CHUNK;

    const f16* cwbG = (const f16*)(ws + WS_CWB);
    const float csq0 = ws[WS_CSQ + a], csq1 = ws[WS_CSQ + a + 16];
    const float nsf0 = ws[WS_NSF + a], nsf1 = ws[WS_NSF + a + 16];

    // ---- cross: wave-local, rows n0+w*16+a, D[n-sub][k] per kt ----
    f32x4 d0 = {0.f, 0.f, 0.f, 0.f}, d1 = {0.f, 0.f, 0.f, 0.f};
    float xs = 0.f;
    {
        const float* xrow = x + (size_t)(b * NN + n0 + w * 16 + a) * CCH;
#pragma unroll
        for (int cs = 0; cs < 16; ++cs) {
            const int c0 = cs * 32 + g * 8;
            const float4 u0 = *reinterpret_cast<const float4*>(xrow + c0);
            const float4 u1 = *reinterpret_cast<const float4*>(xrow + c0 + 4);
            xs += u0.x*u0.x + u0.y*u0.y + u0.z*u0.z + u0.w*u0.w
                + u1.x*u1.x + u1.y*u1.y + u1.z*u1.z + u1.w*u1.w;
            const f16x8 af = {(f16)u0.x, (f16)u0.y, (f16)u0.z, (f16)u0.w,
                              (f16)u1.x, (f16)u1.y, (f16)u1.z, (f16)u1.w};
            const f16x8 bf0 = *reinterpret_cast<const f16x8*>(
                cwbG + ((size_t)cs * 64 + l) * 8);
            const f16x8 bf1 = *reinterpret_cast<const f16x8*>(
                cwbG + ((size_t)(16 + cs) * 64 + l) * 8);
            d0 = __builtin_amdgcn_mfma_f32_16x16x32_f16(af, bf0, d0, 0, 0, 0);
            d1 = __builtin_amdgcn_mfma_f32_16x16x32_f16(af, bf1, d1, 0, 0, 0);
        }
        xs += __shfl_xor(xs, 16);   // reduce x^2 over g-groups: lane holds row (l&15)
        xs += __shfl_xor(xs, 32);
    }

    // ---- softmax: fully in-wave (DPP over k = lane&15 groups) ----
    float wsacc0 = 0.f, wsacc1 = 0.f;
#pragma unroll
    for (int r = 0; r < 4; ++r) {
        const int rho = g * 4 + r;                 // row-sub of D
        const float xsr = __shfl(xs, rho);         // xs of that row (lane rho)
        const float l0 = (xsr - 2.f * d0[r] + csq0) * nsf0;
        const float l1 = (xsr - 2.f * d1[r] + csq1) * nsf1;
        const float mx = rowmax16(fmaxf(l0, l1));
        const float e0 = __expf(l0 - mx);
        const float e1 = __expf(l1 - mx);
        const float inv = 1.f / rowsum16(e0 + e1);
        const float w0 = e0 * inv, w1 = e1 * inv;
        wsacc0 += w0; wsacc1 += w1;
        wexch[(a     ) * 72 + w * 16 + rho] = (f16)w0;
        wexch[(a + 16) * 72 + w * 16 + rho] = (f16)w1;
    }
    wsacc0 += __shfl_xor(wsacc0, 16); wsacc0 += __shfl_xor(wsacc0, 32);
    wsacc1 += __shfl_xor(wsacc1, 16); wsacc1 += __shfl_xor(wsacc1, 32);
    if (l < 16) { wsq[w][l] = wsacc0; wsq[w][l + 16] = wsacc1; }

    __syncthreads();   // the ONLY barrier: wexch/wsq ready

    // ---- wx: A[k][n] from wexch, B[n][c] gathered from global ----
    f32x4 acc[4][2];
#pragma unroll
    for (int ct = 0; ct < 4; ++ct)
#pragma unroll
        for (int kt = 0; kt < 2; ++kt) acc[ct][kt] = (f32x4){0.f, 0.f, 0.f, 0.f};

    const int c0 = z * 256 + w * 64;
#pragma unroll
    for (int sq2 = 0; sq2 < 2; ++sq2) {
        const f16x8 a0 = *reinterpret_cast<const f16x8*>(
            &wexch[(a     ) * 72 + sq2 * 32 + g * 8]);
        const f16x8 a1 = *reinterpret_cast<const f16x8*>(
            &wexch[(a + 16) * 72 + sq2 * 32 + g * 8]);
        const float* xb = x + (size_t)(b * NN + n0 + sq2 * 32 + g * 8) * CCH;
#pragma unroll
        for (int ct = 0; ct < 4; ++ct) {
            const int c = c0 + ct * 16 + a;
            f16x8 B;
#pragma unroll
            for (int i = 0; i < 8; ++i) B[i] = (f16)xb[(size_t)i * CCH + c];
            acc[ct][0] = __builtin_amdgcn_mfma_f32_16x16x32_f16(a0, B, acc[ct][0], 0, 0, 0);
            acc[ct][1] = __builtin_amdgcn_mfma_f32_16x16x32_f16(a1, B, acc[ct][1], 0, 0, 0);
        }
    }

    // ---- store partials: D[k-sub=g*4+reg(+16kt)][c-sub=a] ----
    {
        float* pp = ws + WS_P + ((size_t)(chunk * BB + b)) * CCH * KK;
#pragma unroll
        for (int ct = 0; ct < 4; ++ct) {
            const int c = c0 + ct * 16 + a;
#pragma unroll
            for (int kt = 0; kt < 2; ++kt)
                *reinterpret_cast<f32x4*>(pp + (size_t)c * KK + kt * 16 + g * 4) = acc[ct][kt];
        }
    }
    if (z == 0 && t < KK) {
        ws[WS_WSP + ((size_t)chunk * BB + b) * KK + t] =
            wsq[0][t] + wsq[1][t] + wsq[2][t] + wsq[3][t];
    }
}

// ---------------------------------------------------------------------------
// Kernel R: reduce partials + enc -> BN -> ReLU -> sum_k => encv
// grid (64, 8), 256 thr; thread = (c = cs*8 + t>>5, k = t&31); 8-way ILP.
// ---------------------------------------------------------------------------
__global__ __launch_bounds__(256) void reduce_encv(
    float* __restrict__ ws, const float* __restrict__ cw,
    const float* __restrict__ gamma, const float* __restrict__ beta,
    const float* __restrict__ mean, const float* __restrict__ var)
{
    __shared__ float wsum_s[KK];
    const int b  = blockIdx.y;
    const int cs = blockIdx.x;
    const int t  = threadIdx.x;

    if (t < KK) {
        float s0 = 0.f, s1 = 0.f, s2 = 0.f, s3 = 0.f;
        for (int ch = 0; ch < NBLK; ch += 4) {
            s0 += ws[WS_WSP + ((size_t)(ch + 0) * BB + b) * KK + t];
            s1 += ws[WS_WSP + ((size_t)(ch + 1) * BB + b) * KK + t];
            s2 += ws[WS_WSP + ((size_t)(ch + 2) * BB + b) * KK + t];
            s3 += ws[WS_WSP + ((size_t)(ch + 3) * BB + b) * KK + t];
        }
        wsum_s[t] = s0 + s1 + s2 + s3;
    }
    __syncthreads();

    const int c = cs * 8 + (t >> 5);
    const int k = t & 31;
    const float* p = ws + WS_P + ((size_t)b * CCH + c) * KK + k;
    const size_t stride = (size_t)BB * CCH * KK;

    float a0 = 0.f, a1 = 0.f, a2 = 0.f, a3 = 0.f;
    float a4 = 0.f, a5 = 0.f, a6 = 0.f, a7 = 0.f;
#pragma unroll
    for (int ch = 0; ch < NBLK; ch += 8) {
        a0 += p[(ch + 0) * stride];
        a1 += p[(ch + 1) * stride];
        a2 += p[(ch + 2) * stride];
        a3 += p[(ch + 3) * stride];
        a4 += p[(ch + 4) * stride];
        a5 += p[(ch + 5) * stride];
        a6 += p[(ch + 6) * stride];
        a7 += p[(ch + 7) * stride];
    }
    const float v = ((a0 + a1) + (a2 + a3)) + ((a4 + a5) + (a6 + a7));

    const float g  = gamma[c] * rsqrtf(var[c] + BN_EPS);
    float r = fmaxf((v - cw[c * KK + k] * wsum_s[k] - mean[c]) * g + beta[c], 0.f);
    r += __shfl_xor(r, 1);
    r += __shfl_xor(r, 2);
    r += __shfl_xor(r, 4);
    r += __shfl_xor(r, 8);
    r += __shfl_xor(r, 16);
    if (k == 0) ws[WS_ENC + (size_t)b * CCH + c] = r;
}

// ---------------------------------------------------------------------------
// Kernel B2: attn = sigmoid(encv @ w_enc + b_enc) ; se = sigmoid(encv @ w_se + b_se)
// ---------------------------------------------------------------------------
__global__ __launch_bounds__(256) void attn_se_kernel(
    const float* __restrict__ enc, float* __restrict__ attn,
    const float* __restrict__ w_enc, const float* __restrict__ b_enc,
    const float* __restrict__ w_se, const float* __restrict__ b_se,
    float* __restrict__ out)
{
    __shared__ float ev[CCH];
    __shared__ float red[4][64];
    const int b   = blockIdx.y;
    const int cgb = blockIdx.x;
    const int t   = threadIdx.x;
    ev[t]       = enc[(size_t)b * CCH + t];
    ev[t + 256] = enc[(size_t)b * CCH + 256 + t];
    __syncthreads();
    if (cgb < 8) {
        const int c2 = cgb * 64 + (t & 63);
        const int p  = t >> 6;
        float a = 0.f;
#pragma unroll 4
        for (int i = 0; i < 128; ++i) {
            const int c = p * 128 + i;
            a += ev[c] * w_enc[c * CCH + c2];
        }
        red[p][t & 63] = a;
        __syncthreads();
        if (t < 64) {
            const float v = red[0][t] + red[1][t] + red[2][t] + red[3][t]
                          + b_enc[cgb * 64 + t];
            attn[(size_t)b * CCH + cgb * 64 + t] = 1.f / (1.f + __expf(-v));
        }
    } else if (t < 8 * CLS) {
        const int j = t >> 3, p = t & 7;
        float a = 0.f;
        for (int c = p; c < CCH; c += 8) a += ev[c] * w_se[c * CLS + j];
        a += __shfl_xor(a, 1);
        a += __shfl_xor(a, 2);
        a += __shfl_xor(a, 4);
        if (p == 0)
            out[(size_t)BB * NN * CCH + b * CLS + j] =
                1.f / (1.f + __expf(-(a + b_se[j])));
    }
}

// ---------------------------------------------------------------------------
// Kernel C: featuremaps = attn[b,c] * x
// ---------------------------------------------------------------------------
__global__ __launch_bounds__(256) void scale_out(
    const float* __restrict__ x, const float* __restrict__ attn,
    float* __restrict__ out)
{
    const int gid = blockIdx.x * 256 + threadIdx.x;
    const int c4  = (gid & 127) << 2;
#pragma unroll
    for (int b = 0; b < BB; ++b) {
        const size_t f = ((size_t)b << 19) + (size_t)gid;
        const float4 xv = *reinterpret_cast<const float4*>(x + 4 * f);
        const float4 av = *reinterpret_cast<const float4*>(attn + (size_t)b * CCH + c4);
        float4 o;
        o.x = xv.x * av.x; o.y = xv.y * av.y; o.z = xv.z * av.z; o.w = xv.w * av.w;
        *reinterpret_cast<float4*>(out + 4 * f) = o;
    }
}

// ---------------------------------------------------------------------------
extern "C" void kernel_launch(void* const* d_in, const int* in_sizes, int n_in,
                              void* d_out, int out_size, void* d_ws, size_t ws_size,
                              hipStream_t stream)
{
    const float* x     = (const float*)d_in[0];
    const float* cw    = (const float*)d_in[1];
    const float* sf    = (const float*)d_in[2];
    const float* gamma = (const float*)d_in[3];
    const float* beta  = (const float*)d_in[4];
    const float* mean  = (const float*)d_in[5];
    const float* var   = (const float*)d_in[6];
    const float* w_enc = (const float*)d_in[7];
    const float* b_enc = (const float*)d_in[8];
    const float* w_se  = (const float*)d_in[9];
    const float* b_se  = (const float*)d_in[10];
    float* out = (float*)d_out;
    float* ws  = (float*)d_ws;

    prep_kernel<<<9, 256, 0, stream>>>(cw, sf, ws);
    enc_mfma<<<dim3(NBLK, BB, 2), 256, 0, stream>>>(x, ws);
    reduce_encv<<<dim3(64, BB), 256, 0, stream>>>(ws, cw, gamma, beta, mean, var);
    attn_se_kernel<<<dim3(9, BB), 256, 0, stream>>>(
        ws + WS_ENC, ws + WS_ATTN, w_enc, b_enc, w_se, b_se, out);
    scale_out<<<2048, 256, 0, stream>>>(x, ws + WS_ATTN, out);
}

// Round 11
// 85.047 us; speedup vs baseline: 1.3011x; 1.2276x over previous
//
#include <hip/hip_runtime.h>

#define BB 8
#define NN 4096
#define CCH 512
#define KK 32
#define CLS 21
#define BN_EPS 1e-3f

#define CHUNK 64
#define NBLK (NN / CHUNK)   // 64

typedef _Float16 f16;
typedef _Float16 f16x8 __attribute__((ext_vector_type(8)));
typedef float f32x4 __attribute__((ext_vector_type(4)));

// ws layout (floats)
#define WS_P    0                                  // [NBLK][BB][CCH][KK] fp32 partials
#define WS_WSP  (NBLK * BB * CCH * KK)             // 8388608  [NBLK][BB][KK]
#define WS_ENC  (WS_WSP + NBLK * BB * KK)          // 8404992  [BB][CCH]
#define WS_ATTN (WS_ENC + BB * CCH)                // 8409088  [BB][CCH]
#define WS_CWB  (WS_ATTN + BB * CCH)               // 8413184  f16[2048*8] = 8192 floats
#define WS_CSQ  (WS_CWB + 8192)                    // 8421376  [32]
#define WS_NSF  (WS_CSQ + KK)                      // 8421408  [32]
#define WS_END  (WS_NSF + KK)

template <int CTRL>
__device__ __forceinline__ float dpp_add(float v) {
    int r = __builtin_amdgcn_update_dpp(0, __builtin_bit_cast(int, v),
                                        CTRL, 0xF, 0xF, true);
    return v + __builtin_bit_cast(float, r);
}
template <int CTRL>
__device__ __forceinline__ float dpp_max(float v) {
    int r = __builtin_amdgcn_update_dpp(0, __builtin_bit_cast(int, v),
                                        CTRL, 0xF, 0xF, true);
    return fmaxf(v, __builtin_bit_cast(float, r));
}
__device__ __forceinline__ float rowsum16(float v) {
    v = dpp_add<0x128>(v); v = dpp_add<0x124>(v);
    v = dpp_add<0x122>(v); v = dpp_add<0x121>(v);
    return v;
}
__device__ __forceinline__ float rowmax16(float v) {
    v = dpp_max<0x128>(v); v = dpp_max<0x124>(v);
    v = dpp_max<0x122>(v); v = dpp_max<0x121>(v);
    return v;
}

// ---------------------------------------------------------------------------
// Prep: cwB (B-fragment-layout f16 codewords), csq, nsf -> global ws.
// ---------------------------------------------------------------------------
__global__ __launch_bounds__(256) void prep_kernel(
    const float* __restrict__ cw, const float* __restrict__ sf,
    float* __restrict__ ws)
{
    const int blk = blockIdx.x;
    const int t = threadIdx.x;
    if (blk < 8) {
        const int s     = blk * 256 + t;       // 0..2047
        const int lane  = s & 63;
        const int cstep = (s >> 6) & 15;
        const int kt    = s >> 10;
        const int k     = (lane & 15) + 16 * kt;
        const int c0    = cstep * 32 + (lane >> 4) * 8;
        f16x8 v;
#pragma unroll
        for (int i = 0; i < 8; ++i) v[i] = (f16)cw[(c0 + i) * KK + k];
        reinterpret_cast<f16x8*>(ws + WS_CWB)[s] = v;
    } else {
        __shared__ float red[8][KK];
        const int k = t & 31, part = t >> 5;
        float s = 0.f;
        for (int c = part * 64; c < part * 64 + 64; ++c) {
            const float v = cw[c * KK + k];
            s += v * v;
        }
        red[part][k] = s;
        __syncthreads();
        if (t < KK) {
            float acc = 0.f;
#pragma unroll
            for (int p = 0; p < 8; ++p) acc += red[p][t];
            ws[WS_CSQ + t] = acc;
            ws[WS_NSF + t] = -sf[t];
        }
    }
}

// ---------------------------------------------------------------------------
// Kernel A: per-wave-independent cross+softmax, single barrier, then wx.
// grid (NBLK, BB). Wave w owns rows n0 + w*16..+15 for cross/softmax.
// wx: wave covers c-slice w*128..+127 (16 MFMA), A from wexch LDS,
// B gathered from global x (L1/L2-hot after cross).
// ---------------------------------------------------------------------------
__global__ __launch_bounds__(256, 4) void enc_mfma(
    const float* __restrict__ x, float* __restrict__ ws)
{
    __shared__ f16  wexch[32 * 72];   // [k][64 n], pitch 72 f16
    __shared__ float wsq[4][KK];

    const int t = threadIdx.x;
    const int w = t >> 6, l = t & 63, a = l & 15, g = l >> 4;
    const int chunk = blockIdx.x, b = blockIdx.y;
    const int n0 = chunk * CHUNK;

    const f16* cwbG = (const f16*)(ws + WS_CWB);
    const float csq0 = ws[WS_CSQ + a], csq1 = ws[WS_CSQ + a + 16];
    const float nsf0 = ws[WS_NSF + a], nsf1 = ws[WS_NSF + a + 16];

    // ---- cross: wave-local, rows n0+w*16+a, D[n-sub][k] per kt ----
    f32x4 d0 = {0.f, 0.f, 0.f, 0.f}, d1 = {0.f, 0.f, 0.f, 0.f};
    float xs = 0.f;
    {
        const float* xrow = x + (size_t)(b * NN + n0 + w * 16 + a) * CCH;
#pragma unroll
        for (int cs = 0; cs < 16; ++cs) {
            const int c0 = cs * 32 + g * 8;
            const float4 u0 = *reinterpret_cast<const float4*>(xrow + c0);
            const float4 u1 = *reinterpret_cast<const float4*>(xrow + c0 + 4);
            xs += u0.x*u0.x + u0.y*u0.y + u0.z*u0.z + u0.w*u0.w
                + u1.x*u1.x + u1.y*u1.y + u1.z*u1.z + u1.w*u1.w;
            const f16x8 af = {(f16)u0.x, (f16)u0.y, (f16)u0.z, (f16)u0.w,
                              (f16)u1.x, (f16)u1.y, (f16)u1.z, (f16)u1.w};
            const f16x8 bf0 = *reinterpret_cast<const f16x8*>(
                cwbG + ((size_t)cs * 64 + l) * 8);
            const f16x8 bf1 = *reinterpret_cast<const f16x8*>(
                cwbG + ((size_t)(16 + cs) * 64 + l) * 8);
            d0 = __builtin_amdgcn_mfma_f32_16x16x32_f16(af, bf0, d0, 0, 0, 0);
            d1 = __builtin_amdgcn_mfma_f32_16x16x32_f16(af, bf1, d1, 0, 0, 0);
        }
        xs += __shfl_xor(xs, 16);   // reduce x^2 over g-groups: lane holds row (l&15)
        xs += __shfl_xor(xs, 32);
    }

    // ---- softmax: fully in-wave (DPP over k = lane&15 groups) ----
    float wsacc0 = 0.f, wsacc1 = 0.f;
#pragma unroll
    for (int r = 0; r < 4; ++r) {
        const int rho = g * 4 + r;                 // row-sub of D
        const float xsr = __shfl(xs, rho);         // xs of that row
        const float l0 = (xsr - 2.f * d0[r] + csq0) * nsf0;
        const float l1 = (xsr - 2.f * d1[r] + csq1) * nsf1;
        const float mx = rowmax16(fmaxf(l0, l1));
        const float e0 = __expf(l0 - mx);
        const float e1 = __expf(l1 - mx);
        const float inv = 1.f / rowsum16(e0 + e1);
        const float w0 = e0 * inv, w1 = e1 * inv;
        wsacc0 += w0; wsacc1 += w1;
        wexch[(a     ) * 72 + w * 16 + rho] = (f16)w0;
        wexch[(a + 16) * 72 + w * 16 + rho] = (f16)w1;
    }
    wsacc0 += __shfl_xor(wsacc0, 16); wsacc0 += __shfl_xor(wsacc0, 32);
    wsacc1 += __shfl_xor(wsacc1, 16); wsacc1 += __shfl_xor(wsacc1, 32);
    if (l < 16) { wsq[w][l] = wsacc0; wsq[w][l + 16] = wsacc1; }

    __syncthreads();   // the ONLY barrier: wexch/wsq ready

    // ---- wx: A[k][n] from wexch, B[n][c] gathered from global; 128 c/wave ----
    f32x4 acc[8][2];
#pragma unroll
    for (int ct = 0; ct < 8; ++ct)
#pragma unroll
        for (int kt = 0; kt < 2; ++kt) acc[ct][kt] = (f32x4){0.f, 0.f, 0.f, 0.f};

    const int c0 = w * 128;
#pragma unroll
    for (int sq2 = 0; sq2 < 2; ++sq2) {
        const f16x8 a0 = *reinterpret_cast<const f16x8*>(
            &wexch[(a     ) * 72 + sq2 * 32 + g * 8]);
        const f16x8 a1 = *reinterpret_cast<const f16x8*>(
            &wexch[(a + 16) * 72 + sq2 * 32 + g * 8]);
        const float* xb = x + (size_t)(b * NN + n0 + sq2 * 32 + g * 8) * CCH;
#pragma unroll
        for (int ct = 0; ct < 8; ++ct) {
            const int c = c0 + ct * 16 + a;
            f16x8 B;
#pragma unroll
            for (int i = 0; i < 8; ++i) B[i] = (f16)xb[(size_t)i * CCH + c];
            acc[ct][0] = __builtin_amdgcn_mfma_f32_16x16x32_f16(a0, B, acc[ct][0], 0, 0, 0);
            acc[ct][1] = __builtin_amdgcn_mfma_f32_16x16x32_f16(a1, B, acc[ct][1], 0, 0, 0);
        }
    }

    // ---- store partials: D[k-sub=g*4+reg(+16kt)][c-sub=a] ----
    {
        float* pp = ws + WS_P + ((size_t)(chunk * BB + b)) * CCH * KK;
#pragma unroll
        for (int ct = 0; ct < 8; ++ct) {
            const int c = c0 + ct * 16 + a;
#pragma unroll
            for (int kt = 0; kt < 2; ++kt)
                *reinterpret_cast<f32x4*>(pp + (size_t)c * KK + kt * 16 + g * 4) = acc[ct][kt];
        }
    }
    if (t < KK) {
        ws[WS_WSP + ((size_t)chunk * BB + b) * KK + t] =
            wsq[0][t] + wsq[1][t] + wsq[2][t] + wsq[3][t];
    }
}

// ---------------------------------------------------------------------------
// Kernel R: reduce partials + enc -> BN -> ReLU -> sum_k => encv
// grid (16, 8), 256 thr; thread = (c = cs*32 + t>>3, k4 = t&7) — 1 KB
// contiguous per 8 threads, serial chunk loop with 2-way ILP.
// ---------------------------------------------------------------------------
__global__ __launch_bounds__(256) void reduce_encv(
    float* __restrict__ ws, const float* __restrict__ cw,
    const float* __restrict__ gamma, const float* __restrict__ beta,
    const float* __restrict__ mean, const float* __restrict__ var)
{
    __shared__ float wsum_s[KK];
    const int b  = blockIdx.y;
    const int cs = blockIdx.x;
    const int t  = threadIdx.x;

    if (t < KK) {
        float s0 = 0.f, s1 = 0.f;
        for (int ch = 0; ch < NBLK; ch += 2) {
            s0 += ws[WS_WSP + ((size_t)(ch + 0) * BB + b) * KK + t];
            s1 += ws[WS_WSP + ((size_t)(ch + 1) * BB + b) * KK + t];
        }
        wsum_s[t] = s0 + s1;
    }
    __syncthreads();

    const int cl = t >> 3;
    const int c  = cs * 32 + cl;
    const int kq = t & 7;
    const float* p = ws + WS_P + ((size_t)b * CCH + c) * KK + kq * 4;
    const size_t stride = (size_t)BB * CCH * KK;

    f32x4 a0 = {0.f, 0.f, 0.f, 0.f}, a1 = {0.f, 0.f, 0.f, 0.f};
    for (int ch = 0; ch < NBLK; ch += 2) {
        a0 += *reinterpret_cast<const f32x4*>(p + (ch + 0) * stride);
        a1 += *reinterpret_cast<const f32x4*>(p + (ch + 1) * stride);
    }
    const f32x4 aa = a0 + a1;

    const float g  = gamma[c] * rsqrtf(var[c] + BN_EPS);
    const float mu = mean[c];
    const float be = beta[c];
    const float4 cv = *reinterpret_cast<const float4*>(cw + c * KK + kq * 4);
    const float4 sv = *reinterpret_cast<const float4*>(&wsum_s[kq * 4]);
    float s = 0.f;
    s += fmaxf((aa[0] - cv.x * sv.x - mu) * g + be, 0.f);
    s += fmaxf((aa[1] - cv.y * sv.y - mu) * g + be, 0.f);
    s += fmaxf((aa[2] - cv.z * sv.z - mu) * g + be, 0.f);
    s += fmaxf((aa[3] - cv.w * sv.w - mu) * g + be, 0.f);
    s += __shfl_xor(s, 1);
    s += __shfl_xor(s, 2);
    s += __shfl_xor(s, 4);
    if (kq == 0) ws[WS_ENC + (size_t)b * CCH + c] = s;
}

// ---------------------------------------------------------------------------
// Kernel B2: attn = sigmoid(encv @ w_enc + b_enc) ; se = sigmoid(encv @ w_se + b_se)
// ---------------------------------------------------------------------------
__global__ __launch_bounds__(256) void attn_se_kernel(
    const float* __restrict__ enc, float* __restrict__ attn,
    const float* __restrict__ w_enc, const float* __restrict__ b_enc,
    const float* __restrict__ w_se, const float* __restrict__ b_se,
    float* __restrict__ out)
{
    __shared__ float ev[CCH];
    __shared__ float red[4][64];
    const int b   = blockIdx.y;
    const int cgb = blockIdx.x;
    const int t   = threadIdx.x;
    ev[t]       = enc[(size_t)b * CCH + t];
    ev[t + 256] = enc[(size_t)b * CCH + 256 + t];
    __syncthreads();
    if (cgb < 8) {
        const int c2 = cgb * 64 + (t & 63);
        const int p  = t >> 6;
        float a = 0.f;
#pragma unroll 4
        for (int i = 0; i < 128; ++i) {
            const int c = p * 128 + i;
            a += ev[c] * w_enc[c * CCH + c2];
        }
        red[p][t & 63] = a;
        __syncthreads();
        if (t < 64) {
            const float v = red[0][t] + red[1][t] + red[2][t] + red[3][t]
                          + b_enc[cgb * 64 + t];
            attn[(size_t)b * CCH + cgb * 64 + t] = 1.f / (1.f + __expf(-v));
        }
    } else if (t < 8 * CLS) {
        const int j = t >> 3, p = t & 7;
        float a = 0.f;
        for (int c = p; c < CCH; c += 8) a += ev[c] * w_se[c * CLS + j];
        a += __shfl_xor(a, 1);
        a += __shfl_xor(a, 2);
        a += __shfl_xor(a, 4);
        if (p == 0)
            out[(size_t)BB * NN * CCH + b * CLS + j] =
                1.f / (1.f + __expf(-(a + b_se[j])));
    }
}

// ---------------------------------------------------------------------------
// Kernel C: featuremaps = attn[b,c] * x
// ---------------------------------------------------------------------------
__global__ __launch_bounds__(256) void scale_out(
    const float* __restrict__ x, const float* __restrict__ attn,
    float* __restrict__ out)
{
    const int gid = blockIdx.x * 256 + threadIdx.x;
    const int c4  = (gid & 127) << 2;
#pragma unroll
    for (int b = 0; b < BB; ++b) {
        const size_t f = ((size_t)b << 19) + (size_t)gid;
        const float4 xv = *reinterpret_cast<const float4*>(x + 4 * f);
        const float4 av = *reinterpret_cast<const float4*>(attn + (size_t)b * CCH + c4);
        float4 o;
        o.x = xv.x * av.x; o.y = xv.y * av.y; o.z = xv.z * av.z; o.w = xv.w * av.w;
        *reinterpret_cast<float4*>(out + 4 * f) = o;
    }
}

// ---------------------------------------------------------------------------
extern "C" void kernel_launch(void* const* d_in, const int* in_sizes, int n_in,
                              void* d_out, int out_size, void* d_ws, size_t ws_size,
                              hipStream_t stream)
{
    const float* x     = (const float*)d_in[0];
    const float* cw    = (const float*)d_in[1];
    const float* sf    = (const float*)d_in[2];
    const float* gamma = (const float*)d_in[3];
    const float* beta  = (const float*)d_in[4];
    const float* mean  = (const float*)d_in[5];
    const float* var   = (const float*)d_in[6];
    const float* w_enc = (const float*)d_in[7];
    const float* b_enc = (const float*)d_in[8];
    const float* w_se  = (const float*)d_in[9];
    const float* b_se  = (const float*)d_in[10];
    float* out = (float*)d_out;
    float* ws  = (float*)d_ws;

    prep_kernel<<<9, 256, 0, stream>>>(cw, sf, ws);
    enc_mfma<<<dim3(NBLK, BB), 256, 0, stream>>>(x, ws);
    reduce_encv<<<dim3(16, BB), 256, 0, stream>>>(ws, cw, gamma, beta, mean, var);
    attn_se_kernel<<<dim3(9, BB), 256, 0, stream>>>(
        ws + WS_ENC, ws + WS_ATTN, w_enc, b_enc, w_se, b_se, out);
    scale_out<<<2048, 256, 0, stream>>>(x, ws + WS_ATTN, out);
}

// Round 12
// 81.343 us; speedup vs baseline: 1.3604x; 1.0455x over previous
//
#include <hip/hip_runtime.h>

#define BB 8
#define NN 4096
#define CCH 512
#define KK 32
#define CLS 21
#define BN_EPS 1e-3f

#define CHUNK 128
#define NBLK (NN / CHUNK)   // 32

typedef _Float16 f16;
typedef _Float16 f16x8 __attribute__((ext_vector_type(8)));
typedef float f32x4 __attribute__((ext_vector_type(4)));

#define WP 136   // wexch row pitch in f16 (272 B)

// ws layout (floats)
#define WS_P    0                                  // [NBLK][BB][CCH][KK] fp32 partials
#define WS_WSP  (NBLK * BB * CCH * KK)             // 4194304  [NBLK][BB][KK]
#define WS_ENC  (WS_WSP + NBLK * BB * KK)          // 4202496  [BB][CCH]
#define WS_ATTN (WS_ENC + BB * CCH)                // 4206592  [BB][CCH]
#define WS_CWB  (WS_ATTN + BB * CCH)               // 4210688  f16[2048*8] = 8192 floats
#define WS_CSQ  (WS_CWB + 8192)                    // 4218880  [32]
#define WS_NSF  (WS_CSQ + KK)                      // [32]
#define WS_END  (WS_NSF + KK)

template <int CTRL>
__device__ __forceinline__ float dpp_add(float v) {
    int r = __builtin_amdgcn_update_dpp(0, __builtin_bit_cast(int, v),
                                        CTRL, 0xF, 0xF, true);
    return v + __builtin_bit_cast(float, r);
}
template <int CTRL>
__device__ __forceinline__ float dpp_max(float v) {
    int r = __builtin_amdgcn_update_dpp(0, __builtin_bit_cast(int, v),
                                        CTRL, 0xF, 0xF, true);
    return fmaxf(v, __builtin_bit_cast(float, r));
}
__device__ __forceinline__ float rowsum16(float v) {
    v = dpp_add<0x128>(v); v = dpp_add<0x124>(v);
    v = dpp_add<0x122>(v); v = dpp_add<0x121>(v);
    return v;
}
__device__ __forceinline__ float rowmax16(float v) {
    v = dpp_max<0x128>(v); v = dpp_max<0x124>(v);
    v = dpp_max<0x122>(v); v = dpp_max<0x121>(v);
    return v;
}

// ---------------------------------------------------------------------------
// Prep: cwB (B-fragment-layout f16 codewords), csq, nsf -> global ws.
// ---------------------------------------------------------------------------
__global__ __launch_bounds__(256) void prep_kernel(
    const float* __restrict__ cw, const float* __restrict__ sf,
    float* __restrict__ ws)
{
    const int blk = blockIdx.x;
    const int t = threadIdx.x;
    if (blk < 8) {
        const int s     = blk * 256 + t;       // 0..2047
        const int lane  = s & 63;
        const int cstep = (s >> 6) & 15;
        const int kt    = s >> 10;
        const int k     = (lane & 15) + 16 * kt;
        const int c0    = cstep * 32 + (lane >> 4) * 8;
        f16x8 v;
#pragma unroll
        for (int i = 0; i < 8; ++i) v[i] = (f16)cw[(c0 + i) * KK + k];
        reinterpret_cast<f16x8*>(ws + WS_CWB)[s] = v;
    } else {
        __shared__ float red[8][KK];
        const int k = t & 31, part = t >> 5;
        float s = 0.f;
        for (int c = part * 64; c < part * 64 + 64; ++c) {
            const float v = cw[c * KK + k];
            s += v * v;
        }
        red[part][k] = s;
        __syncthreads();
        if (t < KK) {
            float acc = 0.f;
#pragma unroll
            for (int p = 0; p < 8; ++p) acc += red[p][t];
            ws[WS_CSQ + t] = acc;
            ws[WS_NSF + t] = -sf[t];
        }
    }
}

// ---------------------------------------------------------------------------
// Kernel A: 8 waves, 128-row chunk, single barrier.
// Cross/softmax: wave w owns rows n0+w*16..+15, all 512 c, all 32 k in-wave.
// wx: wave covers c-slice w*64..+63 over K=128 rows (4 K-steps, 32 MFMA).
// ---------------------------------------------------------------------------
__global__ __launch_bounds__(512, 2) void enc_mfma(
    const float* __restrict__ x, float* __restrict__ ws)
{
    __shared__ f16  wexch[32 * WP];   // [k][128 n]
    __shared__ float wsq[8][KK];

    const int t = threadIdx.x;
    const int w = t >> 6, l = t & 63, a = l & 15, g = l >> 4;
    const int chunk = blockIdx.x, b = blockIdx.y;
    const int n0 = chunk * CHUNK;

    const f16* cwbG = (const f16*)(ws + WS_CWB);
    const float csq0 = ws[WS_CSQ + a], csq1 = ws[WS_CSQ + a + 16];
    const float nsf0 = ws[WS_NSF + a], nsf1 = ws[WS_NSF + a + 16];

    // ---- cross: wave-local, rows n0+w*16+a ----
    f32x4 d0 = {0.f, 0.f, 0.f, 0.f}, d1 = {0.f, 0.f, 0.f, 0.f};
    float xs = 0.f;
    {
        const float* xrow = x + (size_t)(b * NN + n0 + w * 16 + a) * CCH;
#pragma unroll
        for (int cs = 0; cs < 16; ++cs) {
            const int c0 = cs * 32 + g * 8;
            const float4 u0 = *reinterpret_cast<const float4*>(xrow + c0);
            const float4 u1 = *reinterpret_cast<const float4*>(xrow + c0 + 4);
            xs += u0.x*u0.x + u0.y*u0.y + u0.z*u0.z + u0.w*u0.w
                + u1.x*u1.x + u1.y*u1.y + u1.z*u1.z + u1.w*u1.w;
            const f16x8 af = {(f16)u0.x, (f16)u0.y, (f16)u0.z, (f16)u0.w,
                              (f16)u1.x, (f16)u1.y, (f16)u1.z, (f16)u1.w};
            const f16x8 bf0 = *reinterpret_cast<const f16x8*>(
                cwbG + ((size_t)cs * 64 + l) * 8);
            const f16x8 bf1 = *reinterpret_cast<const f16x8*>(
                cwbG + ((size_t)(16 + cs) * 64 + l) * 8);
            d0 = __builtin_amdgcn_mfma_f32_16x16x32_f16(af, bf0, d0, 0, 0, 0);
            d1 = __builtin_amdgcn_mfma_f32_16x16x32_f16(af, bf1, d1, 0, 0, 0);
        }
        xs += __shfl_xor(xs, 16);
        xs += __shfl_xor(xs, 32);
    }

    // ---- softmax: fully in-wave ----
    float wsacc0 = 0.f, wsacc1 = 0.f;
#pragma unroll
    for (int r = 0; r < 4; ++r) {
        const int rho = g * 4 + r;
        const float xsr = __shfl(xs, rho);
        const float l0 = (xsr - 2.f * d0[r] + csq0) * nsf0;
        const float l1 = (xsr - 2.f * d1[r] + csq1) * nsf1;
        const float mx = rowmax16(fmaxf(l0, l1));
        const float e0 = __expf(l0 - mx);
        const float e1 = __expf(l1 - mx);
        const float inv = 1.f / rowsum16(e0 + e1);
        const float w0 = e0 * inv, w1 = e1 * inv;
        wsacc0 += w0; wsacc1 += w1;
        wexch[(a     ) * WP + w * 16 + rho] = (f16)w0;
        wexch[(a + 16) * WP + w * 16 + rho] = (f16)w1;
    }
    wsacc0 += __shfl_xor(wsacc0, 16); wsacc0 += __shfl_xor(wsacc0, 32);
    wsacc1 += __shfl_xor(wsacc1, 16); wsacc1 += __shfl_xor(wsacc1, 32);
    if (l < 16) { wsq[w][l] = wsacc0; wsq[w][l + 16] = wsacc1; }

    __syncthreads();   // the ONLY barrier

    // ---- wx: A[k][n] from wexch, B[n][c] gathered from global; 64 c/wave ----
    f32x4 acc[4][2];
#pragma unroll
    for (int ct = 0; ct < 4; ++ct)
#pragma unroll
        for (int kt = 0; kt < 2; ++kt) acc[ct][kt] = (f32x4){0.f, 0.f, 0.f, 0.f};

    const int c0 = w * 64;
#pragma unroll
    for (int sq2 = 0; sq2 < 4; ++sq2) {
        const f16x8 a0 = *reinterpret_cast<const f16x8*>(
            &wexch[(a     ) * WP + sq2 * 32 + g * 8]);
        const f16x8 a1 = *reinterpret_cast<const f16x8*>(
            &wexch[(a + 16) * WP + sq2 * 32 + g * 8]);
        const float* xb = x + (size_t)(b * NN + n0 + sq2 * 32 + g * 8) * CCH;
#pragma unroll
        for (int ct = 0; ct < 4; ++ct) {
            const int c = c0 + ct * 16 + a;
            f16x8 B;
#pragma unroll
            for (int i = 0; i < 8; ++i) B[i] = (f16)xb[(size_t)i * CCH + c];
            acc[ct][0] = __builtin_amdgcn_mfma_f32_16x16x32_f16(a0, B, acc[ct][0], 0, 0, 0);
            acc[ct][1] = __builtin_amdgcn_mfma_f32_16x16x32_f16(a1, B, acc[ct][1], 0, 0, 0);
        }
    }

    // ---- store partials ----
    {
        float* pp = ws + WS_P + ((size_t)(chunk * BB + b)) * CCH * KK;
#pragma unroll
        for (int ct = 0; ct < 4; ++ct) {
            const int c = c0 + ct * 16 + a;
#pragma unroll
            for (int kt = 0; kt < 2; ++kt)
                *reinterpret_cast<f32x4*>(pp + (size_t)c * KK + kt * 16 + g * 4) = acc[ct][kt];
        }
    }
    if (t < KK) {
        float s = 0.f;
#pragma unroll
        for (int p = 0; p < 8; ++p) s += wsq[p][t];
        ws[WS_WSP + ((size_t)chunk * BB + b) * KK + t] = s;
    }
}

// ---------------------------------------------------------------------------
// Kernel R: reduce partials + enc -> BN -> ReLU -> sum_k => encv
// grid (16, 8); thread = (c = cs*32 + t>>3, kq = t&7); serial chunk loop.
// ---------------------------------------------------------------------------
__global__ __launch_bounds__(256) void reduce_encv(
    float* __restrict__ ws, const float* __restrict__ cw,
    const float* __restrict__ gamma, const float* __restrict__ beta,
    const float* __restrict__ mean, const float* __restrict__ var)
{
    __shared__ float wsum_s[KK];
    const int b  = blockIdx.y;
    const int cs = blockIdx.x;
    const int t  = threadIdx.x;

    if (t < KK) {
        float s0 = 0.f, s1 = 0.f;
        for (int ch = 0; ch < NBLK; ch += 2) {
            s0 += ws[WS_WSP + ((size_t)(ch + 0) * BB + b) * KK + t];
            s1 += ws[WS_WSP + ((size_t)(ch + 1) * BB + b) * KK + t];
        }
        wsum_s[t] = s0 + s1;
    }
    __syncthreads();

    const int cl = t >> 3;
    const int c  = cs * 32 + cl;
    const int kq = t & 7;
    const float* p = ws + WS_P + ((size_t)b * CCH + c) * KK + kq * 4;
    const size_t stride = (size_t)BB * CCH * KK;

    f32x4 a0 = {0.f, 0.f, 0.f, 0.f}, a1 = {0.f, 0.f, 0.f, 0.f};
    for (int ch = 0; ch < NBLK; ch += 2) {
        a0 += *reinterpret_cast<const f32x4*>(p + (ch + 0) * stride);
        a1 += *reinterpret_cast<const f32x4*>(p + (ch + 1) * stride);
    }
    const f32x4 aa = a0 + a1;

    const float g  = gamma[c] * rsqrtf(var[c] + BN_EPS);
    const float mu = mean[c];
    const float be = beta[c];
    const float4 cv = *reinterpret_cast<const float4*>(cw + c * KK + kq * 4);
    const float4 sv = *reinterpret_cast<const float4*>(&wsum_s[kq * 4]);
    float s = 0.f;
    s += fmaxf((aa[0] - cv.x * sv.x - mu) * g + be, 0.f);
    s += fmaxf((aa[1] - cv.y * sv.y - mu) * g + be, 0.f);
    s += fmaxf((aa[2] - cv.z * sv.z - mu) * g + be, 0.f);
    s += fmaxf((aa[3] - cv.w * sv.w - mu) * g + be, 0.f);
    s += __shfl_xor(s, 1);
    s += __shfl_xor(s, 2);
    s += __shfl_xor(s, 4);
    if (kq == 0) ws[WS_ENC + (size_t)b * CCH + c] = s;
}

// ---------------------------------------------------------------------------
// Kernel B2: attn = sigmoid(encv @ w_enc + b_enc) ; se = sigmoid(encv @ w_se + b_se)
// ---------------------------------------------------------------------------
__global__ __launch_bounds__(256) void attn_se_kernel(
    const float* __restrict__ enc, float* __restrict__ attn,
    const float* __restrict__ w_enc, const float* __restrict__ b_enc,
    const float* __restrict__ w_se, const float* __restrict__ b_se,
    float* __restrict__ out)
{
    __shared__ float ev[CCH];
    __shared__ float red[4][64];
    const int b   = blockIdx.y;
    const int cgb = blockIdx.x;
    const int t   = threadIdx.x;
    ev[t]       = enc[(size_t)b * CCH + t];
    ev[t + 256] = enc[(size_t)b * CCH + 256 + t];
    __syncthreads();
    if (cgb < 8) {
        const int c2 = cgb * 64 + (t & 63);
        const int p  = t >> 6;
        float a = 0.f;
#pragma unroll 4
        for (int i = 0; i < 128; ++i) {
            const int c = p * 128 + i;
            a += ev[c] * w_enc[c * CCH + c2];
        }
        red[p][t & 63] = a;
        __syncthreads();
        if (t < 64) {
            const float v = red[0][t] + red[1][t] + red[2][t] + red[3][t]
                          + b_enc[cgb * 64 + t];
            attn[(size_t)b * CCH + cgb * 64 + t] = 1.f / (1.f + __expf(-v));
        }
    } else if (t < 8 * CLS) {
        const int j = t >> 3, p = t & 7;
        float a = 0.f;
        for (int c = p; c < CCH; c += 8) a += ev[c] * w_se[c * CLS + j];
        a += __shfl_xor(a, 1);
        a += __shfl_xor(a, 2);
        a += __shfl_xor(a, 4);
        if (p == 0)
            out[(size_t)BB * NN * CCH + b * CLS + j] =
                1.f / (1.f + __expf(-(a + b_se[j])));
    }
}

// ---------------------------------------------------------------------------
// Kernel C: featuremaps = attn[b,c] * x  (nontemporal streams)
// ---------------------------------------------------------------------------
__global__ __launch_bounds__(256) void scale_out(
    const float* __restrict__ x, const float* __restrict__ attn,
    float* __restrict__ out)
{
    const int gid = blockIdx.x * 256 + threadIdx.x;
    const int c4  = (gid & 127) << 2;
#pragma unroll
    for (int b = 0; b < BB; ++b) {
        const size_t f = ((size_t)b << 19) + (size_t)gid;
        const f32x4 xv = __builtin_nontemporal_load(
            reinterpret_cast<const f32x4*>(x + 4 * f));
        const f32x4 av = *reinterpret_cast<const f32x4*>(attn + (size_t)b * CCH + c4);
        __builtin_nontemporal_store(xv * av, reinterpret_cast<f32x4*>(out + 4 * f));
    }
}

// ---------------------------------------------------------------------------
extern "C" void kernel_launch(void* const* d_in, const int* in_sizes, int n_in,
                              void* d_out, int out_size, void* d_ws, size_t ws_size,
                              hipStream_t stream)
{
    const float* x     = (const float*)d_in[0];
    const float* cw    = (const float*)d_in[1];
    const float* sf    = (const float*)d_in[2];
    const float* gamma = (const float*)d_in[3];
    const float* beta  = (const float*)d_in[4];
    const float* mean  = (const float*)d_in[5];
    const float* var   = (const float*)d_in[6];
    const float* w_enc = (const float*)d_in[7];
    const float* b_enc = (const float*)d_in[8];
    const float* w_se  = (const float*)d_in[9];
    const float* b_se  = (const float*)d_in[10];
    float* out = (float*)d_out;
    float* ws  = (float*)d_ws;

    prep_kernel<<<9, 256, 0, stream>>>(cw, sf, ws);
    enc_mfma<<<dim3(NBLK, BB), 512, 0, stream>>>(x, ws);
    reduce_encv<<<dim3(16, BB), 256, 0, stream>>>(ws, cw, gamma, beta, mean, var);
    attn_se_kernel<<<dim3(9, BB), 256, 0, stream>>>(
        ws + WS_ENC, ws + WS_ATTN, w_enc, b_enc, w_se, b_se, out);
    scale_out<<<2048, 256, 0, stream>>>(x, ws + WS_ATTN, out);
}